// Round 5
// baseline (107.634 us; speedup 1.0000x reference)
//
#include <hip/hip_runtime.h>
#include <math.h>

// GPR_58746562675312: haversine-windowed weighted mean.
//   m[y] = sum_x w(y,x)*x[x] / sum_x w(y,x),  w = d if d<0.25 else 0,
//   d = 12.756 * asin(sqrt(hav(y,x)));  out = [m (ny), 0.001 (ny)]
//
// R12: model from R8/R10/R11: dur = F(~40us harness ws-poison fill)
// + ~6us/dispatch + build(~10) + main(~10). R11's YPW=2 regressed
// (latency-bound main needs TLP) -> main reverted to R8's proven
// gpr_binned. Build pipeline restructured 4 -> 2 dispatches:
//   1) hist_part: per-block LDS hist of a 256-pt chunk -> private
//      partial slice (no zero kernel, no global atomics)
//   2) scan_scatter: each block redundantly sums partials + LDS
//      Hillis-Steele scan (R10-proven shape), computes its disjoint
//      per-cell ranges, scatters its chunk via LDS cursors.
// Total 3 dispatches vs R8's 5 (predict ~-12us).
// Cutoff radius 1.123 deg (reference uses sin(D), not sin(D/2)).
// Boundary decisions: band +-5e-8 on hav -> CR fp32-chain emulation.

#define TPB    256
#define YPB    4      // y rows per block == waves per block (main kernel)
#define CH     256    // points per build chunk
#define STPB   1024   // scan_scatter block size
#define NSTRIP 40
#define NLON   40
#define NCELLS (NSTRIP * NLON)
#define C_CELL   0.25f
#define INV_CELL 4.0f
#define RLAT     1.1250f   // conservative window radius in degrees

__device__ __forceinline__ float sin_poly(float a) {
    float t = a * a;   // |a| <= 0.1746: err ~1e-9
    return a * fmaf(t, fmaf(t, 8.3333333e-3f, -0.16666667f), 1.0f);
}
__device__ __forceinline__ float cos_poly(float a) {
    float t = a * a;   // err ~2e-11
    return fmaf(t, fmaf(t, fmaf(t, -1.3888889e-3f, 4.1666668e-2f), -0.5f), 1.0f);
}
__device__ __forceinline__ int cell_of(float lon, float lat) {
    int s = (int)(lat * INV_CELL); s = min(max(s, 0), NSTRIP - 1);
    int l = (int)(lon * INV_CELL); l = min(max(l, 0), NLON - 1);
    return s * NLON + l;
}

// ---- build 1: per-chunk partial histograms (no zero, no global atomics)
// blocks [0, nbx) handle x chunks; blocks [nbx, nbx+nby) handle y chunks.

__global__ __launch_bounds__(TPB) void hist_part(
    const float* __restrict__ x_l, const float* __restrict__ y_l,
    int* __restrict__ partX, int* __restrict__ partY,
    int nx, int ny, int nbx)
{
    __shared__ int h[NCELLS];
    const int tid = threadIdx.x;
    const bool isX = ((int)blockIdx.x < nbx);
    const int  bd  = isX ? blockIdx.x : blockIdx.x - nbx;
    const int  n   = isX ? nx : ny;
    const float* loc = isX ? x_l : y_l;
    int* part = isX ? partX : partY;

    for (int c = tid; c < NCELLS; c += TPB) h[c] = 0;
    __syncthreads();

    int i = bd * CH + tid;
    if (tid < CH && i < n)
        atomicAdd(&h[cell_of(loc[2 * i], loc[2 * i + 1])], 1);
    __syncthreads();

    for (int c = tid; c < NCELLS; c += TPB) part[bd * NCELLS + c] = h[c];
}

// ---- build 2: redundant scan + disjoint-range scatter ------------------
// Every block recomputes its domain's per-cell totals + its own prefix,
// scans in LDS (R10-proven Hillis-Steele shape), then scatters its chunk
// into deterministic disjoint per-cell ranges via LDS cursors.

__global__ __launch_bounds__(STPB) void scan_scatter(
    const float* __restrict__ x, const float* __restrict__ x_l,
    const float* __restrict__ y_l,
    const int* __restrict__ partX, const int* __restrict__ partY,
    float4* __restrict__ sortedA, float2* __restrict__ sortedRaw,
    float*  __restrict__ sortedX,
    float2* __restrict__ sortedYL, int* __restrict__ sortedYIdx,
    int* __restrict__ csX, int nx, int ny, int nbx, int nby)
{
    __shared__ int curls[NCELLS];
    __shared__ int sums[STPB];
    const int tid = threadIdx.x;
    const float d2r = 0.017453292519943295f;

    const bool isX = ((int)blockIdx.x < nbx);
    const int  bd  = isX ? blockIdx.x : blockIdx.x - nbx;
    const int  ndom = isX ? nx : ny;
    const int  nbd  = isX ? nbx : nby;
    const float* loc = isX ? x_l : y_l;
    const int* part  = isX ? partX : partY;

    // per-thread: totals + my-prefix for cells c0 = 2*tid, c1 = 2*tid+1
    const int c0 = 2 * tid, c1 = c0 + 1;
    int t0 = 0, t1 = 0, p0 = 0, p1 = 0;
    const bool v0 = (c0 < NCELLS), v1 = (c1 < NCELLS);
    for (int q = 0; q < nbd; ++q) {
        int a0 = v0 ? part[q * NCELLS + c0] : 0;
        int a1 = v1 ? part[q * NCELLS + c1] : 0;
        t0 += a0; t1 += a1;
        if (q < bd) { p0 += a0; p1 += a1; }
    }

    // exclusive scan over cell totals (Hillis-Steele, R10-proven)
    sums[tid] = t0 + t1;
    __syncthreads();
    for (int off = 1; off < STPB; off <<= 1) {
        int t = (tid >= off) ? sums[tid - off] : 0;
        __syncthreads();
        sums[tid] += t;
        __syncthreads();
    }
    int excl = (tid > 0) ? sums[tid - 1] : 0;

    // cursors = cellStart + prefix-of-earlier-blocks (disjoint ranges)
    if (v0) curls[c0] = excl + p0;
    if (v1) curls[c1] = excl + t0 + p1;
    if (isX && bd == 0) {
        if (v0) csX[c0] = excl;
        if (v1) csX[c1] = excl + t0;
        if (tid == STPB - 1) csX[NCELLS] = sums[STPB - 1];
    }
    __syncthreads();

    // scatter this block's chunk (one point per thread, CH <= STPB)
    int i = bd * CH + tid;
    if (tid < CH && i < ndom) {
        float lon = loc[2 * i], lat = loc[2 * i + 1];
        int pos = atomicAdd(&curls[cell_of(lon, lat)], 1);
        if (isX) {
            float al = lat * d2r, ao = lon * d2r;
            sortedA[pos]   = make_float4(sin_poly(al), cos_poly(al),
                                         sin_poly(ao), cos_poly(ao));
            sortedRaw[pos] = make_float2(lon, lat);
            sortedX[pos]   = x[i];
        } else {
            sortedYL[pos]   = make_float2(lon, lat);
            sortedYIdx[pos] = i;
        }
    }
}

// ---- main kernel (binned, y processed in sorted order; R8-identical) ---

__global__ __launch_bounds__(TPB) void gpr_binned(
    const float4* __restrict__ sortedA,   // (slat, clat, slon, clon)
    const float2* __restrict__ sortedRaw, // (lon, lat) raw degrees
    const float*  __restrict__ sortedX,
    const int*    __restrict__ cellStart, // [NCELLS+1] (x grid)
    const float2* __restrict__ sortedYL,
    const int*    __restrict__ sortedYIdx,
    float* __restrict__ out, int ny, float Hcut, float HcutM)
{
    const int tid  = threadIdx.x;
    const int wave = tid >> 6;
    const int lane = tid & 63;
    const int j    = blockIdx.x * YPB + wave;   // sorted-y position

    const float d2r    = 0.017453292519943295f;
    const float r2d    = 57.29577951308232f;
    const float THRESH = 0.25f;
    const float DIAM   = 12.756f;
    const float DIAM6  = 12.756f / 6.0f;
    const float EPS_H  = 5e-8f;

    int   yidx  = 0;
    float lon_y = 0.0f, lat_y = 0.0f;
    if (j < ny) {
        yidx = sortedYIdx[j];
        float2 p = sortedYL[j];
        lon_y = p.x; lat_y = p.y;
    }
    const float sly   = sin_poly(lat_y * d2r);
    const float cly   = cos_poly(lat_y * d2r);
    const float slony = sin_poly(lon_y * d2r);
    const float clony = cos_poly(lon_y * d2r);

    float accw = 0.0f, accwx = 0.0f;

    const int s0 = max(0,          (int)floorf((lat_y - RLAT) * INV_CELL));
    const int s1 = min(NSTRIP - 1, (int)floorf((lat_y + RLAT) * INV_CELL));

    for (int s = s0; s <= s1; ++s) {
        // conservative min |dlat| from y to this strip
        float slo = s * C_CELL, shi = slo + C_CELL;
        float dmin = fmaxf(0.0f, fmaxf(slo - lat_y, lat_y - shi));
        float de   = fmaxf(0.0f, dmin - 3e-3f);
        float sd_  = sin_poly(de * d2r);
        float rem  = HcutM - sd_ * sd_;
        if (rem <= 0.0f) continue;
        // conservative min cos(lat_x)*cos(lat_y) over the strip
        float ccm = cos_poly(fminf(shi, 10.0f) * d2r) * cly * 0.999999f;
        float W   = asinf(fminf(1.0f, sqrtf(rem / ccm))) * r2d + 4e-3f;
        int lo = min(NLON - 1, max(0, (int)floorf((lon_y - W) * INV_CELL)));
        int hi = min(NLON - 1, max(0, (int)floorf((lon_y + W) * INV_CELL)));
        int p0 = cellStart[s * NLON + lo];
        int p1 = cellStart[s * NLON + hi + 1];

        for (int k = p0 + lane; k < p1; k += 64) {
            float4 e  = sortedA[k];
            float  xv = sortedX[k];

            float sl  = fmaf(e.x, cly,   -(e.y * sly));    // sin(dlat*d2r)
            float sd  = fmaf(e.z, clony, -(e.w * slony));  // sin(dlon*d2r)
            float cxy = e.y * cly;
            float hav = fmaf(sl, sl, cxy * (sd * sd));

            float tb  = hav - Hcut;
            float r   = __builtin_amdgcn_sqrtf(hav);
            float d   = r * fmaf(hav, DIAM6, DIAM);

            float w;
            if (__builtin_expect(fabsf(tb) < EPS_H, 0)) {
                // Emulate the numpy fp32 chain, every step correctly rounded.
                float2 raw = sortedRaw[k];
                float lonx = raw.x, latx = raw.y;

                float dlat = __fsub_rn(latx, lat_y);
                float alat = __fmul_rn(dlat, d2r);
                float slf  = (float)sin((double)alat);        // CR fp32 sin
                float h1   = __fmul_rn(slf, slf);

                float axl  = __fmul_rn(latx,  d2r);
                float ayl  = __fmul_rn(lat_y, d2r);
                float cxf  = (float)cos((double)axl);         // CR fp32 cos
                float cyf  = (float)cos((double)ayl);
                float cc   = __fmul_rn(cxf, cyf);

                float dlon = __fsub_rn(lonx, lon_y);
                float alon = __fmul_rn(dlon, d2r);
                float sdf  = (float)sin((double)alon);
                float h2   = __fmul_rn(sdf, sdf);

                float hv   = __fadd_rn(h1, __fmul_rn(cc, h2));
                float r32  = (float)sqrt((double)hv);         // CR fp32 sqrt
                float as32 = (float)asin((double)r32);        // CR fp32 asin
                float dnp  = __fmul_rn(DIAM, as32);
                w = (dnp < THRESH) ? dnp : 0.0f;
            } else {
                w = (tb < 0.0f) ? d : 0.0f;
            }

            accw += w;
            accwx = fmaf(w, xv, accwx);
        }
    }

    #pragma unroll
    for (int off = 32; off > 0; off >>= 1) {
        accw  += __shfl_xor(accw,  off, 64);
        accwx += __shfl_xor(accwx, off, 64);
    }

    if (lane == 0 && j < ny) {
        float m = (accw > 0.0f) ? (accwx / fmaxf(accw, 1e-12f)) : 0.0f;
        out[yidx]      = m;
        out[ny + yidx] = 0.001f;
    }
}

// ---- fallback: full scan (used only if ws is too small) ---------------

__global__ __launch_bounds__(TPB) void gpr_full(
    const float* __restrict__ x, const float* __restrict__ x_l,
    const float* __restrict__ y_l, float* __restrict__ out,
    int nx, int ny, float Hcut)
{
    __shared__ float4 tA[1024];
    __shared__ float  tX[1024];

    const int tid  = threadIdx.x;
    const int wave = tid >> 6;
    const int lane = tid & 63;
    const int y    = blockIdx.x * YPB + wave;

    const float d2r    = 0.017453292519943295f;
    const float THRESH = 0.25f;
    const float DIAM   = 12.756f;
    const float DIAM6  = 12.756f / 6.0f;
    const float EPS_H  = 5e-8f;

    float lon_y = 0.0f, lat_y = 0.0f;
    if (y < ny) { lon_y = y_l[2 * y]; lat_y = y_l[2 * y + 1]; }
    const float sly   = sin_poly(lat_y * d2r);
    const float cly   = cos_poly(lat_y * d2r);
    const float slony = sin_poly(lon_y * d2r);
    const float clony = cos_poly(lon_y * d2r);

    float accw = 0.0f, accwx = 0.0f;

    const int ntiles = (nx + 1023) / 1024;
    for (int t = 0; t < ntiles; ++t) {
        const int base = t * 1024;
        __syncthreads();
        #pragma unroll
        for (int jj = 0; jj < 1024 / TPB; ++jj) {
            int idx = jj * TPB + tid, i = base + idx;
            if (i < nx) {
                float lon = x_l[2 * i], lat = x_l[2 * i + 1];
                tA[idx] = make_float4(sin_poly(lat * d2r), cos_poly(lat * d2r),
                                      sin_poly(lon * d2r), cos_poly(lon * d2r));
                tX[idx] = x[i];
            }
        }
        __syncthreads();

        const int tn = min(1024, nx - base);
        for (int k = lane; k < tn; k += 64) {
            float4 e  = tA[k];
            float  xv = tX[k];
            float sl  = fmaf(e.x, cly,   -(e.y * sly));
            float sd  = fmaf(e.z, clony, -(e.w * slony));
            float cxy = e.y * cly;
            float hav = fmaf(sl, sl, cxy * (sd * sd));
            float tb  = hav - Hcut;
            float r   = __builtin_amdgcn_sqrtf(hav);
            float d   = r * fmaf(hav, DIAM6, DIAM);
            float w;
            if (__builtin_expect(fabsf(tb) < EPS_H, 0)) {
                int   i    = base + k;
                float lonx = x_l[2 * i], latx = x_l[2 * i + 1];
                float dlat = __fsub_rn(latx, lat_y);
                float alat = __fmul_rn(dlat, d2r);
                float slf  = (float)sin((double)alat);
                float h1   = __fmul_rn(slf, slf);
                float axl  = __fmul_rn(latx,  d2r);
                float ayl  = __fmul_rn(lat_y, d2r);
                float cxf  = (float)cos((double)axl);
                float cyf  = (float)cos((double)ayl);
                float cc   = __fmul_rn(cxf, cyf);
                float dlon = __fsub_rn(lonx, lon_y);
                float alon = __fmul_rn(dlon, d2r);
                float sdf  = (float)sin((double)alon);
                float h2   = __fmul_rn(sdf, sdf);
                float hv   = __fadd_rn(h1, __fmul_rn(cc, h2));
                float r32  = (float)sqrt((double)hv);
                float as32 = (float)asin((double)r32);
                float dnp  = __fmul_rn(DIAM, as32);
                w = (dnp < THRESH) ? dnp : 0.0f;
            } else {
                w = (tb < 0.0f) ? d : 0.0f;
            }
            accw += w;
            accwx = fmaf(w, xv, accwx);
        }
    }

    #pragma unroll
    for (int off = 32; off > 0; off >>= 1) {
        accw  += __shfl_xor(accw,  off, 64);
        accwx += __shfl_xor(accwx, off, 64);
    }

    if (lane == 0 && y < ny) {
        float m = (accw > 0.0f) ? (accwx / fmaxf(accw, 1e-12f)) : 0.0f;
        out[y]      = m;
        out[ny + y] = 0.001f;
    }
}

// ---- launcher ----------------------------------------------------------

extern "C" void kernel_launch(void* const* d_in, const int* in_sizes, int n_in,
                              void* d_out, int out_size, void* d_ws, size_t ws_size,
                              hipStream_t stream) {
    const float* x   = (const float*)d_in[0];
    const float* x_l = (const float*)d_in[1];
    const float* y_l = (const float*)d_in[2];
    float* out = (float*)d_out;

    const int nx = in_sizes[0];        // 20000
    const int ny = in_sizes[2] / 2;    // 6000

    const int nbx = (nx + CH - 1) / CH;   // 79
    const int nby = (ny + CH - 1) / CH;   // 24

    // hav threshold, fp64 on host: sin^2(0.25/12.756)
    double th = 0.25 / 12.756;
    double s  = sin(th);
    float Hcut  = (float)(s * s);
    float HcutM = (float)(s * s * 1.001);   // margin for window pruning

    // ws layout (16B-aligned start; 8/4-byte members naturally aligned)
    size_t offA   = 0;
    size_t offRaw = offA   + (size_t)nx * sizeof(float4);       // 16 nx
    size_t offYL  = offRaw + (size_t)nx * sizeof(float2);       //  8 nx
    size_t offX   = offYL  + (size_t)ny * sizeof(float2);       //  8 ny
    size_t offYI  = offX   + (size_t)nx * sizeof(float);        //  4 nx
    size_t offCSX = offYI  + (size_t)ny * sizeof(int);          //  4 ny
    size_t offPX  = offCSX + (size_t)(NCELLS + 1) * sizeof(int);
    size_t offPY  = offPX  + (size_t)nbx * NCELLS * sizeof(int);
    size_t total  = offPY  + (size_t)nby * NCELLS * sizeof(int);

    const int blocks = (ny + YPB - 1) / YPB;

    if (ws_size >= total) {
        float4* sortedA    = (float4*)((char*)d_ws + offA);
        float2* sortedRaw  = (float2*)((char*)d_ws + offRaw);
        float2* sortedYL   = (float2*)((char*)d_ws + offYL);
        float*  sortedX    = (float*) ((char*)d_ws + offX);
        int*    sortedYIdx = (int*)   ((char*)d_ws + offYI);
        int*    csX        = (int*)   ((char*)d_ws + offCSX);
        int*    partX      = (int*)   ((char*)d_ws + offPX);
        int*    partY      = (int*)   ((char*)d_ws + offPY);

        hist_part<<<nbx + nby, TPB, 0, stream>>>(x_l, y_l, partX, partY,
                                                 nx, ny, nbx);
        scan_scatter<<<nbx + nby, STPB, 0, stream>>>(x, x_l, y_l,
                                                     partX, partY,
                                                     sortedA, sortedRaw, sortedX,
                                                     sortedYL, sortedYIdx,
                                                     csX, nx, ny, nbx, nby);
        gpr_binned<<<blocks, TPB, 0, stream>>>(sortedA, sortedRaw, sortedX,
                                               csX, sortedYL, sortedYIdx,
                                               out, ny, Hcut, HcutM);
    } else {
        gpr_full<<<blocks, TPB, 0, stream>>>(x, x_l, y_l, out, nx, ny, Hcut);
    }
}

// Round 6
// 105.846 us; speedup vs baseline: 1.0169x; 1.0169x over previous
//
#include <hip/hip_runtime.h>
#include <math.h>

// GPR_58746562675312: haversine-windowed weighted mean.
//   m[y] = sum_x w(y,x)*x[x] / sum_x w(y,x),  w = d if d<0.25 else 0,
//   d = 12.756 * asin(sqrt(hav(y,x)));  out = [m (ny), 0.001 (ny)]
//
// R13: model from R8..R12: dur = ~40us (harness ws-poison fill) +
// sum(kernel times) + ~6us/dispatch-node. Counting sort replaced by a
// fixed-capacity bucket grid (K=64 slots/cell; P(overflow) ~1e-24 for
// 20000 uniform pts over 1600 cells): no zero/hist/scan dispatches.
//   D1 hipMemsetAsync(cnt, 0, 6.4KB)
//   D2 append: pos = atomicAdd(&cnt[cell]); bucket[cell*K+pos] = pt
//   D3 main: per y, per strip (R8-identical pruning math), per cell:
//      n = min(cnt,K) <= 64 = wave size -> ONE predicated body, no
//      inner loop; fused 2-cell half-wave pass when both n <= 32.
// y is processed UNSORTED (x buckets are L2-resident; R11 showed y-sort
// only bought marginal locality). Per-point arithmetic byte-identical
// to the R8-proven chain (incl. CR fp32 boundary-band emulation).
// Cutoff radius 1.123 deg (reference uses sin(D), not sin(D/2)).

#define TPB    256
#define YPB    4      // y rows per block == waves per block (main kernel)
#define NSTRIP 40
#define NLON   40
#define NCELLS (NSTRIP * NLON)
#define KCAP   64     // bucket capacity per cell (== wave size)
#define C_CELL   0.25f
#define INV_CELL 4.0f
#define RLAT     1.1250f   // conservative window radius in degrees

__device__ __forceinline__ float sin_poly(float a) {
    float t = a * a;   // |a| <= 0.1746: err ~1e-9
    return a * fmaf(t, fmaf(t, 8.3333333e-3f, -0.16666667f), 1.0f);
}
__device__ __forceinline__ float cos_poly(float a) {
    float t = a * a;   // err ~2e-11
    return fmaf(t, fmaf(t, fmaf(t, -1.3888889e-3f, 4.1666668e-2f), -0.5f), 1.0f);
}
__device__ __forceinline__ int cell_of(float lon, float lat) {
    int s = (int)(lat * INV_CELL); s = min(max(s, 0), NSTRIP - 1);
    int l = (int)(lon * INV_CELL); l = min(max(l, 0), NLON - 1);
    return s * NLON + l;
}

// ---- build: single append kernel (cnt pre-zeroed by memsetAsync) -------

__global__ __launch_bounds__(TPB) void append_kernel(
    const float* __restrict__ x, const float* __restrict__ x_l,
    int* __restrict__ cnt,
    float4* __restrict__ bA, float2* __restrict__ bRaw,
    float*  __restrict__ bX, int nx)
{
    const float d2r = 0.017453292519943295f;
    int i = blockIdx.x * TPB + threadIdx.x;
    if (i >= nx) return;
    float lon = x_l[2 * i], lat = x_l[2 * i + 1];
    int cell = cell_of(lon, lat);
    int pos = atomicAdd(&cnt[cell], 1);
    if (pos < KCAP) {   // overflow prob ~1e-24; guard keeps writes in-bounds
        int idx = cell * KCAP + pos;
        float al = lat * d2r, ao = lon * d2r;
        bA[idx]   = make_float4(sin_poly(al), cos_poly(al),
                                sin_poly(ao), cos_poly(ao));
        bRaw[idx] = make_float2(lon, lat);
        bX[idx]   = x[i];
    }
}

// ---- per-point body (byte-identical arithmetic to R8's gpr_binned) -----

__device__ __forceinline__ void point_body(
    const float4* __restrict__ bA, const float2* __restrict__ bRaw,
    const float*  __restrict__ bX, int idx,
    float sly, float cly, float slony, float clony,
    float lon_y, float lat_y, float Hcut,
    float& accw, float& accwx)
{
    const float d2r    = 0.017453292519943295f;
    const float THRESH = 0.25f;
    const float DIAM   = 12.756f;
    const float DIAM6  = 12.756f / 6.0f;
    const float EPS_H  = 5e-8f;

    float4 e  = bA[idx];
    float  xv = bX[idx];

    float sl  = fmaf(e.x, cly,   -(e.y * sly));    // sin(dlat*d2r)
    float sd  = fmaf(e.z, clony, -(e.w * slony));  // sin(dlon*d2r)
    float cxy = e.y * cly;
    float hav = fmaf(sl, sl, cxy * (sd * sd));

    float tb  = hav - Hcut;
    float r   = __builtin_amdgcn_sqrtf(hav);
    float d   = r * fmaf(hav, DIAM6, DIAM);

    float w;
    if (__builtin_expect(fabsf(tb) < EPS_H, 0)) {
        // Emulate the numpy fp32 chain, every step correctly rounded.
        float2 raw = bRaw[idx];
        float lonx = raw.x, latx = raw.y;

        float dlat = __fsub_rn(latx, lat_y);
        float alat = __fmul_rn(dlat, d2r);
        float slf  = (float)sin((double)alat);        // CR fp32 sin
        float h1   = __fmul_rn(slf, slf);

        float axl  = __fmul_rn(latx,  d2r);
        float ayl  = __fmul_rn(lat_y, d2r);
        float cxf  = (float)cos((double)axl);         // CR fp32 cos
        float cyf  = (float)cos((double)ayl);
        float cc   = __fmul_rn(cxf, cyf);

        float dlon = __fsub_rn(lonx, lon_y);
        float alon = __fmul_rn(dlon, d2r);
        float sdf  = (float)sin((double)alon);
        float h2   = __fmul_rn(sdf, sdf);

        float hv   = __fadd_rn(h1, __fmul_rn(cc, h2));
        float r32  = (float)sqrt((double)hv);         // CR fp32 sqrt
        float as32 = (float)asin((double)r32);        // CR fp32 asin
        float dnp  = __fmul_rn(DIAM, as32);
        w = (dnp < THRESH) ? dnp : 0.0f;
    } else {
        w = (tb < 0.0f) ? d : 0.0f;
    }

    accw += w;
    accwx = fmaf(w, xv, accwx);
}

// ---- main kernel: bucket-grid traversal, y unsorted --------------------

__global__ __launch_bounds__(TPB) void gpr_bucket(
    const float4* __restrict__ bA, const float2* __restrict__ bRaw,
    const float*  __restrict__ bX, const int* __restrict__ cnt,
    const float*  __restrict__ y_l,
    float* __restrict__ out, int ny, float Hcut, float HcutM)
{
    const int tid  = threadIdx.x;
    const int wave = tid >> 6;
    const int lane = tid & 63;
    const int j    = blockIdx.x * YPB + wave;   // y index (unsorted)

    const float d2r = 0.017453292519943295f;
    const float r2d = 57.29577951308232f;

    float lon_y = 0.0f, lat_y = 0.0f;
    if (j < ny) { lon_y = y_l[2 * j]; lat_y = y_l[2 * j + 1]; }

    const float sly   = sin_poly(lat_y * d2r);
    const float cly   = cos_poly(lat_y * d2r);
    const float slony = sin_poly(lon_y * d2r);
    const float clony = cos_poly(lon_y * d2r);

    float accw = 0.0f, accwx = 0.0f;

    const int s0 = max(0,          (int)floorf((lat_y - RLAT) * INV_CELL));
    const int s1 = min(NSTRIP - 1, (int)floorf((lat_y + RLAT) * INV_CELL));

    for (int s = s0; s <= s1; ++s) {
        // conservative min |dlat| from y to this strip (R8-identical)
        float slo = s * C_CELL, shi = slo + C_CELL;
        float dmin = fmaxf(0.0f, fmaxf(slo - lat_y, lat_y - shi));
        float de   = fmaxf(0.0f, dmin - 3e-3f);
        float sd_  = sin_poly(de * d2r);
        float rem  = HcutM - sd_ * sd_;
        if (rem <= 0.0f) continue;
        float ccm = cos_poly(fminf(shi, 10.0f) * d2r) * cly * 0.999999f;
        float W   = asinf(fminf(1.0f, sqrtf(rem / ccm))) * r2d + 4e-3f;
        int lo = min(NLON - 1, max(0, (int)floorf((lon_y - W) * INV_CELL)));
        int hi = min(NLON - 1, max(0, (int)floorf((lon_y + W) * INV_CELL)));

        int c = lo;
        while (c <= hi) {
            int cell0 = s * NLON + c;
            int n0 = min(cnt[cell0], KCAP);
            if (c < hi) {
                int n1 = min(cnt[cell0 + 1], KCAP);
                if ((n0 <= 32) & (n1 <= 32)) {
                    // fused pass: half-wave per cell
                    int half = lane >> 5;          // 0 or 1
                    int slot = lane & 31;
                    int cc   = cell0 + half;
                    int nn   = half ? n1 : n0;
                    if (slot < nn)
                        point_body(bA, bRaw, bX, cc * KCAP + slot,
                                   sly, cly, slony, clony,
                                   lon_y, lat_y, Hcut, accw, accwx);
                    c += 2;
                    continue;
                }
            }
            // single-cell pass (n0 <= 64 == wave size: one predicated body)
            if (lane < n0)
                point_body(bA, bRaw, bX, cell0 * KCAP + lane,
                           sly, cly, slony, clony,
                           lon_y, lat_y, Hcut, accw, accwx);
            c += 1;
        }
    }

    #pragma unroll
    for (int off = 32; off > 0; off >>= 1) {
        accw  += __shfl_xor(accw,  off, 64);
        accwx += __shfl_xor(accwx, off, 64);
    }

    if (lane == 0 && j < ny) {
        float m = (accw > 0.0f) ? (accwx / fmaxf(accw, 1e-12f)) : 0.0f;
        out[j]      = m;
        out[ny + j] = 0.001f;
    }
}

// ---- fallback: full scan (used only if ws is too small) ---------------

__global__ __launch_bounds__(TPB) void gpr_full(
    const float* __restrict__ x, const float* __restrict__ x_l,
    const float* __restrict__ y_l, float* __restrict__ out,
    int nx, int ny, float Hcut)
{
    __shared__ float4 tA[1024];
    __shared__ float  tX[1024];

    const int tid  = threadIdx.x;
    const int wave = tid >> 6;
    const int lane = tid & 63;
    const int y    = blockIdx.x * YPB + wave;

    const float d2r    = 0.017453292519943295f;
    const float THRESH = 0.25f;
    const float DIAM   = 12.756f;
    const float DIAM6  = 12.756f / 6.0f;
    const float EPS_H  = 5e-8f;

    float lon_y = 0.0f, lat_y = 0.0f;
    if (y < ny) { lon_y = y_l[2 * y]; lat_y = y_l[2 * y + 1]; }
    const float sly   = sin_poly(lat_y * d2r);
    const float cly   = cos_poly(lat_y * d2r);
    const float slony = sin_poly(lon_y * d2r);
    const float clony = cos_poly(lon_y * d2r);

    float accw = 0.0f, accwx = 0.0f;

    const int ntiles = (nx + 1023) / 1024;
    for (int t = 0; t < ntiles; ++t) {
        const int base = t * 1024;
        __syncthreads();
        #pragma unroll
        for (int jj = 0; jj < 1024 / TPB; ++jj) {
            int idx = jj * TPB + tid, i = base + idx;
            if (i < nx) {
                float lon = x_l[2 * i], lat = x_l[2 * i + 1];
                tA[idx] = make_float4(sin_poly(lat * d2r), cos_poly(lat * d2r),
                                      sin_poly(lon * d2r), cos_poly(lon * d2r));
                tX[idx] = x[i];
            }
        }
        __syncthreads();

        const int tn = min(1024, nx - base);
        for (int k = lane; k < tn; k += 64) {
            float4 e  = tA[k];
            float  xv = tX[k];
            float sl  = fmaf(e.x, cly,   -(e.y * sly));
            float sd  = fmaf(e.z, clony, -(e.w * slony));
            float cxy = e.y * cly;
            float hav = fmaf(sl, sl, cxy * (sd * sd));
            float tb  = hav - Hcut;
            float r   = __builtin_amdgcn_sqrtf(hav);
            float d   = r * fmaf(hav, DIAM6, DIAM);
            float w;
            if (__builtin_expect(fabsf(tb) < EPS_H, 0)) {
                int   i    = base + k;
                float lonx = x_l[2 * i], latx = x_l[2 * i + 1];
                float dlat = __fsub_rn(latx, lat_y);
                float alat = __fmul_rn(dlat, d2r);
                float slf  = (float)sin((double)alat);
                float h1   = __fmul_rn(slf, slf);
                float axl  = __fmul_rn(latx,  d2r);
                float ayl  = __fmul_rn(lat_y, d2r);
                float cxf  = (float)cos((double)axl);
                float cyf  = (float)cos((double)ayl);
                float cc   = __fmul_rn(cxf, cyf);
                float dlon = __fsub_rn(lonx, lon_y);
                float alon = __fmul_rn(dlon, d2r);
                float sdf  = (float)sin((double)alon);
                float h2   = __fmul_rn(sdf, sdf);
                float hv   = __fadd_rn(h1, __fmul_rn(cc, h2));
                float r32  = (float)sqrt((double)hv);
                float as32 = (float)asin((double)r32);
                float dnp  = __fmul_rn(DIAM, as32);
                w = (dnp < THRESH) ? dnp : 0.0f;
            } else {
                w = (tb < 0.0f) ? d : 0.0f;
            }
            accw += w;
            accwx = fmaf(w, xv, accwx);
        }
    }

    #pragma unroll
    for (int off = 32; off > 0; off >>= 1) {
        accw  += __shfl_xor(accw,  off, 64);
        accwx += __shfl_xor(accwx, off, 64);
    }

    if (lane == 0 && y < ny) {
        float m = (accw > 0.0f) ? (accwx / fmaxf(accw, 1e-12f)) : 0.0f;
        out[y]      = m;
        out[ny + y] = 0.001f;
    }
}

// ---- launcher ----------------------------------------------------------

extern "C" void kernel_launch(void* const* d_in, const int* in_sizes, int n_in,
                              void* d_out, int out_size, void* d_ws, size_t ws_size,
                              hipStream_t stream) {
    const float* x   = (const float*)d_in[0];
    const float* x_l = (const float*)d_in[1];
    const float* y_l = (const float*)d_in[2];
    float* out = (float*)d_out;

    const int nx = in_sizes[0];        // 20000
    const int ny = in_sizes[2] / 2;    // 6000

    // hav threshold, fp64 on host: sin^2(0.25/12.756)
    double th = 0.25 / 12.756;
    double s  = sin(th);
    float Hcut  = (float)(s * s);
    float HcutM = (float)(s * s * 1.001);   // margin for window pruning

    // ws layout (16B-aligned members)
    size_t offBA  = 0;
    size_t offBR  = offBA + (size_t)NCELLS * KCAP * sizeof(float4);  // 1.64 MB
    size_t offBX  = offBR + (size_t)NCELLS * KCAP * sizeof(float2);  // 0.82 MB
    size_t offCnt = offBX + (size_t)NCELLS * KCAP * sizeof(float);   // 0.41 MB
    size_t total  = offCnt + (size_t)NCELLS * sizeof(int);           // 6.4 KB

    const int blocks = (ny + YPB - 1) / YPB;

    if (ws_size >= total) {
        float4* bA   = (float4*)((char*)d_ws + offBA);
        float2* bRaw = (float2*)((char*)d_ws + offBR);
        float*  bX   = (float*) ((char*)d_ws + offBX);
        int*    cnt  = (int*)   ((char*)d_ws + offCnt);

        hipMemsetAsync(cnt, 0, (size_t)NCELLS * sizeof(int), stream);
        int nb = (nx + TPB - 1) / TPB;
        append_kernel<<<nb, TPB, 0, stream>>>(x, x_l, cnt, bA, bRaw, bX, nx);
        gpr_bucket<<<blocks, TPB, 0, stream>>>(bA, bRaw, bX, cnt, y_l,
                                               out, ny, Hcut, HcutM);
    } else {
        gpr_full<<<blocks, TPB, 0, stream>>>(x, x_l, y_l, out, nx, ny, Hcut);
    }
}

// Round 9
// 103.932 us; speedup vs baseline: 1.0356x; 1.0184x over previous
//
#include <hip/hip_runtime.h>
#include <math.h>

// GPR_58746562675312: haversine-windowed weighted mean.
//   m[y] = sum_x w(y,x)*x[x] / sum_x w(y,x),  w = d if d<0.25 else 0,
//   d = 12.756 * asin(sqrt(hav(y,x)));  out = [m (ny), 0.001 (ny)]
//
// R16: identical to R15. R15's bench died with "container failed twice"
// (infra-level: no pytest output, no verdict) -- same signature as R0,
// where an identical resubmission then passed. Source audit found no
// hang/OOB/capture hazard: pipeline is the R13-proven 3-node shape
// (memsetAsync 6.4KB + append + main), loops bounded (T <= 2560, fixed
// 6-step search), all indices clamped, all shuffles full-exec.
//
// R15 content: R14's compacted traversal with the divergent-__shfl bug
// fixed (count load + window shuffle executed UNCONDITIONALLY by all 64
// lanes with clamped indices, masked afterwards; inactive-source-lane
// reads were the absmax=1.07 cause).
//   main: per strip, prefetch cnt row; in-register exclusive prefix
//   (6x shfl_up); iterate compacted slots g=g0+lane < T; map g ->
//   (cell,slot) by 6-step shfl binary search. Lane util ~20% -> ~87%.
// Per-point arithmetic byte-identical to the R8-proven chain (incl. CR
// fp32 boundary-band emulation). Cutoff radius 1.123 deg.

#define TPB    256
#define YPB    4      // y rows per block == waves per block (main kernel)
#define NSTRIP 40
#define NLON   40
#define NCELLS (NSTRIP * NLON)
#define KCAP   64     // bucket capacity per cell (P(overflow) ~1e-24)
#define C_CELL   0.25f
#define INV_CELL 4.0f
#define RLAT     1.1250f   // conservative window radius in degrees

__device__ __forceinline__ float sin_poly(float a) {
    float t = a * a;   // |a| <= 0.1746: err ~1e-9
    return a * fmaf(t, fmaf(t, 8.3333333e-3f, -0.16666667f), 1.0f);
}
__device__ __forceinline__ float cos_poly(float a) {
    float t = a * a;   // err ~2e-11
    return fmaf(t, fmaf(t, fmaf(t, -1.3888889e-3f, 4.1666668e-2f), -0.5f), 1.0f);
}
__device__ __forceinline__ int cell_of(float lon, float lat) {
    int s = (int)(lat * INV_CELL); s = min(max(s, 0), NSTRIP - 1);
    int l = (int)(lon * INV_CELL); l = min(max(l, 0), NLON - 1);
    return s * NLON + l;
}

// ---- build: single append kernel (cnt pre-zeroed by memsetAsync) -------

__global__ __launch_bounds__(TPB) void append_kernel(
    const float* __restrict__ x, const float* __restrict__ x_l,
    int* __restrict__ cnt,
    float4* __restrict__ bA, float2* __restrict__ bRaw,
    float*  __restrict__ bX, int nx)
{
    const float d2r = 0.017453292519943295f;
    int i = blockIdx.x * TPB + threadIdx.x;
    if (i >= nx) return;
    float2 ll = ((const float2*)x_l)[i];
    float lon = ll.x, lat = ll.y;
    int cell = cell_of(lon, lat);
    int pos = atomicAdd(&cnt[cell], 1);
    if (pos < KCAP) {   // overflow prob ~1e-24; guard keeps writes in-bounds
        int idx = cell * KCAP + pos;
        float al = lat * d2r, ao = lon * d2r;
        bA[idx]   = make_float4(sin_poly(al), cos_poly(al),
                                sin_poly(ao), cos_poly(ao));
        bRaw[idx] = make_float2(lon, lat);
        bX[idx]   = x[i];
    }
}

// ---- per-point body (byte-identical arithmetic to R8's gpr_binned) -----

__device__ __forceinline__ void point_body(
    const float4* __restrict__ bA, const float2* __restrict__ bRaw,
    const float*  __restrict__ bX, int idx,
    float sly, float cly, float slony, float clony,
    float lon_y, float lat_y, float Hcut,
    float& accw, float& accwx)
{
    const float d2r    = 0.017453292519943295f;
    const float THRESH = 0.25f;
    const float DIAM   = 12.756f;
    const float DIAM6  = 12.756f / 6.0f;
    const float EPS_H  = 5e-8f;

    float4 e  = bA[idx];
    float  xv = bX[idx];

    float sl  = fmaf(e.x, cly,   -(e.y * sly));    // sin(dlat*d2r)
    float sd  = fmaf(e.z, clony, -(e.w * slony));  // sin(dlon*d2r)
    float cxy = e.y * cly;
    float hav = fmaf(sl, sl, cxy * (sd * sd));

    float tb  = hav - Hcut;
    float r   = __builtin_amdgcn_sqrtf(hav);
    float d   = r * fmaf(hav, DIAM6, DIAM);

    float w;
    if (__builtin_expect(fabsf(tb) < EPS_H, 0)) {
        // Emulate the numpy fp32 chain, every step correctly rounded.
        float2 raw = bRaw[idx];
        float lonx = raw.x, latx = raw.y;

        float dlat = __fsub_rn(latx, lat_y);
        float alat = __fmul_rn(dlat, d2r);
        float slf  = (float)sin((double)alat);        // CR fp32 sin
        float h1   = __fmul_rn(slf, slf);

        float axl  = __fmul_rn(latx,  d2r);
        float ayl  = __fmul_rn(lat_y, d2r);
        float cxf  = (float)cos((double)axl);         // CR fp32 cos
        float cyf  = (float)cos((double)ayl);
        float cc   = __fmul_rn(cxf, cyf);

        float dlon = __fsub_rn(lonx, lon_y);
        float alon = __fmul_rn(dlon, d2r);
        float sdf  = (float)sin((double)alon);
        float h2   = __fmul_rn(sdf, sdf);

        float hv   = __fadd_rn(h1, __fmul_rn(cc, h2));
        float r32  = (float)sqrt((double)hv);         // CR fp32 sqrt
        float as32 = (float)asin((double)r32);        // CR fp32 asin
        float dnp  = __fmul_rn(DIAM, as32);
        w = (dnp < THRESH) ? dnp : 0.0f;
    } else {
        w = (tb < 0.0f) ? d : 0.0f;
    }

    accw += w;
    accwx = fmaf(w, xv, accwx);
}

// ---- main kernel: compacted bucket traversal ---------------------------

__global__ __launch_bounds__(TPB) void gpr_compact(
    const float4* __restrict__ bA, const float2* __restrict__ bRaw,
    const float*  __restrict__ bX, const int* __restrict__ cnt,
    const float*  __restrict__ y_l,
    float* __restrict__ out, int ny, float Hcut, float HcutM)
{
    const int tid  = threadIdx.x;
    const int wave = tid >> 6;
    const int lane = tid & 63;
    const int j    = blockIdx.x * YPB + wave;   // y index (unsorted)

    const float d2r = 0.017453292519943295f;
    const float r2d = 57.29577951308232f;

    float lon_y = 0.0f, lat_y = 0.0f;
    if (j < ny) {
        float2 p = ((const float2*)y_l)[j];
        lon_y = p.x; lat_y = p.y;
    }

    const float sly   = sin_poly(lat_y * d2r);
    const float cly   = cos_poly(lat_y * d2r);
    const float slony = sin_poly(lon_y * d2r);
    const float clony = cos_poly(lon_y * d2r);

    float accw = 0.0f, accwx = 0.0f;

    const int s0 = max(0,          (int)floorf((lat_y - RLAT) * INV_CELL));
    const int s1 = min(NSTRIP - 1, (int)floorf((lat_y + RLAT) * INV_CELL));

    for (int s = s0; s <= s1; ++s) {
        // prefetch this strip's cnt row -- UNCONDITIONAL (all 64 lanes,
        // clamped index) so later shuffles have all source lanes active
        int cr = cnt[s * NLON + min(lane, NLON - 1)];

        // conservative window math (R8-identical)
        float slo = s * C_CELL, shi = slo + C_CELL;
        float dmin = fmaxf(0.0f, fmaxf(slo - lat_y, lat_y - shi));
        float de   = fmaxf(0.0f, dmin - 3e-3f);
        float sd_  = sin_poly(de * d2r);
        float rem  = HcutM - sd_ * sd_;
        if (rem <= 0.0f) continue;
        float ccm = cos_poly(fminf(shi, 10.0f) * d2r) * cly * 0.999999f;
        float W   = asinf(fminf(1.0f, sqrtf(rem / ccm))) * r2d + 4e-3f;
        int lo = min(NLON - 1, max(0, (int)floorf((lon_y - W) * INV_CELL)));
        int hi = min(NLON - 1, max(0, (int)floorf((lon_y + W) * INV_CELL)));

        const int ncell = hi - lo + 1;            // 1..40 (<= 64)
        const int cbase = s * NLON + lo;

        // per-lane cell count within the window: shuffle executed by ALL
        // lanes (clamped source), mask applied AFTER (R14 bugfix)
        int v  = __shfl(cr, min(lo + lane, NLON - 1), 64);
        int nc = (lane < ncell) ? min(v, KCAP) : 0;

        // inclusive prefix over 64 lanes (lanes >= ncell contribute 0)
        int pfx = nc;
        #pragma unroll
        for (int o = 1; o < 64; o <<= 1) {
            int t = __shfl_up(pfx, o, 64);
            if (lane >= o) pfx += t;
        }
        const int T   = __shfl(pfx, 63, 64);      // total points in window
        const int stc = pfx - nc;                 // exclusive start, my cell

        for (int g0 = 0; g0 < T; g0 += 64) {
            int g  = g0 + lane;
            int gc = min(g, T - 1);               // clamp: uniform search

            // find c = last window-cell with start <= gc (6 steps, ncell<=40)
            int lo_ = 0, hi_ = ncell - 1, sc = 0;
            #pragma unroll
            for (int it = 0; it < 6; ++it) {
                int mid  = (lo_ + hi_ + 1) >> 1;
                int smid = __shfl(stc, mid, 64);
                if (smid <= gc) { lo_ = mid; sc = smid; }
                else            { hi_ = mid - 1; }
            }
            int idx = (cbase + lo_) * KCAP + (gc - sc);
            if (g < T)
                point_body(bA, bRaw, bX, idx,
                           sly, cly, slony, clony,
                           lon_y, lat_y, Hcut, accw, accwx);
        }
    }

    #pragma unroll
    for (int off = 32; off > 0; off >>= 1) {
        accw  += __shfl_xor(accw,  off, 64);
        accwx += __shfl_xor(accwx, off, 64);
    }

    if (lane == 0 && j < ny) {
        float m = (accw > 0.0f) ? (accwx / fmaxf(accw, 1e-12f)) : 0.0f;
        out[j]      = m;
        out[ny + j] = 0.001f;
    }
}

// ---- fallback: full scan (used only if ws is too small) ---------------

__global__ __launch_bounds__(TPB) void gpr_full(
    const float* __restrict__ x, const float* __restrict__ x_l,
    const float* __restrict__ y_l, float* __restrict__ out,
    int nx, int ny, float Hcut)
{
    __shared__ float4 tA[1024];
    __shared__ float  tX[1024];

    const int tid  = threadIdx.x;
    const int wave = tid >> 6;
    const int lane = tid & 63;
    const int y    = blockIdx.x * YPB + wave;

    const float d2r    = 0.017453292519943295f;
    const float THRESH = 0.25f;
    const float DIAM   = 12.756f;
    const float DIAM6  = 12.756f / 6.0f;
    const float EPS_H  = 5e-8f;

    float lon_y = 0.0f, lat_y = 0.0f;
    if (y < ny) { lon_y = y_l[2 * y]; lat_y = y_l[2 * y + 1]; }
    const float sly   = sin_poly(lat_y * d2r);
    const float cly   = cos_poly(lat_y * d2r);
    const float slony = sin_poly(lon_y * d2r);
    const float clony = cos_poly(lon_y * d2r);

    float accw = 0.0f, accwx = 0.0f;

    const int ntiles = (nx + 1023) / 1024;
    for (int t = 0; t < ntiles; ++t) {
        const int base = t * 1024;
        __syncthreads();
        #pragma unroll
        for (int jj = 0; jj < 1024 / TPB; ++jj) {
            int idx = jj * TPB + tid, i = base + idx;
            if (i < nx) {
                float lon = x_l[2 * i], lat = x_l[2 * i + 1];
                tA[idx] = make_float4(sin_poly(lat * d2r), cos_poly(lat * d2r),
                                      sin_poly(lon * d2r), cos_poly(lon * d2r));
                tX[idx] = x[i];
            }
        }
        __syncthreads();

        const int tn = min(1024, nx - base);
        for (int k = lane; k < tn; k += 64) {
            float4 e  = tA[k];
            float  xv = tX[k];
            float sl  = fmaf(e.x, cly,   -(e.y * sly));
            float sd  = fmaf(e.z, clony, -(e.w * slony));
            float cxy = e.y * cly;
            float hav = fmaf(sl, sl, cxy * (sd * sd));
            float tb  = hav - Hcut;
            float r   = __builtin_amdgcn_sqrtf(hav);
            float d   = r * fmaf(hav, DIAM6, DIAM);
            float w;
            if (__builtin_expect(fabsf(tb) < EPS_H, 0)) {
                int   i    = base + k;
                float lonx = x_l[2 * i], latx = x_l[2 * i + 1];
                float dlat = __fsub_rn(latx, lat_y);
                float alat = __fmul_rn(dlat, d2r);
                float slf  = (float)sin((double)alat);
                float h1   = __fmul_rn(slf, slf);
                float axl  = __fmul_rn(latx,  d2r);
                float ayl  = __fmul_rn(lat_y, d2r);
                float cxf  = (float)cos((double)axl);
                float cyf  = (float)cos((double)ayl);
                float cc   = __fmul_rn(cxf, cyf);
                float dlon = __fsub_rn(lonx, lon_y);
                float alon = __fmul_rn(dlon, d2r);
                float sdf  = (float)sin((double)alon);
                float h2   = __fmul_rn(sdf, sdf);
                float hv   = __fadd_rn(h1, __fmul_rn(cc, h2));
                float r32  = (float)sqrt((double)hv);
                float as32 = (float)asin((double)r32);
                float dnp  = __fmul_rn(DIAM, as32);
                w = (dnp < THRESH) ? dnp : 0.0f;
            } else {
                w = (tb < 0.0f) ? d : 0.0f;
            }
            accw += w;
            accwx = fmaf(w, xv, accwx);
        }
    }

    #pragma unroll
    for (int off = 32; off > 0; off >>= 1) {
        accw  += __shfl_xor(accw,  off, 64);
        accwx += __shfl_xor(accwx, off, 64);
    }

    if (lane == 0 && y < ny) {
        float m = (accw > 0.0f) ? (accwx / fmaxf(accw, 1e-12f)) : 0.0f;
        out[y]      = m;
        out[ny + y] = 0.001f;
    }
}

// ---- launcher ----------------------------------------------------------

extern "C" void kernel_launch(void* const* d_in, const int* in_sizes, int n_in,
                              void* d_out, int out_size, void* d_ws, size_t ws_size,
                              hipStream_t stream) {
    const float* x   = (const float*)d_in[0];
    const float* x_l = (const float*)d_in[1];
    const float* y_l = (const float*)d_in[2];
    float* out = (float*)d_out;

    const int nx = in_sizes[0];        // 20000
    const int ny = in_sizes[2] / 2;    // 6000

    // hav threshold, fp64 on host: sin^2(0.25/12.756)
    double th = 0.25 / 12.756;
    double s  = sin(th);
    float Hcut  = (float)(s * s);
    float HcutM = (float)(s * s * 1.001);   // margin for window pruning

    // ws layout (16B-aligned members)
    size_t offBA  = 0;
    size_t offBR  = offBA + (size_t)NCELLS * KCAP * sizeof(float4);  // 1.64 MB
    size_t offBX  = offBR + (size_t)NCELLS * KCAP * sizeof(float2);  // 0.82 MB
    size_t offCnt = offBX + (size_t)NCELLS * KCAP * sizeof(float);   // 0.41 MB
    size_t total  = offCnt + (size_t)NCELLS * sizeof(int);           // 6.4 KB

    const int blocks = (ny + YPB - 1) / YPB;

    if (ws_size >= total) {
        float4* bA   = (float4*)((char*)d_ws + offBA);
        float2* bRaw = (float2*)((char*)d_ws + offBR);
        float*  bX   = (float*) ((char*)d_ws + offBX);
        int*    cnt  = (int*)   ((char*)d_ws + offCnt);

        hipMemsetAsync(cnt, 0, (size_t)NCELLS * sizeof(int), stream);
        int nb = (nx + TPB - 1) / TPB;
        append_kernel<<<nb, TPB, 0, stream>>>(x, x_l, cnt, bA, bRaw, bX, nx);
        gpr_compact<<<blocks, TPB, 0, stream>>>(bA, bRaw, bX, cnt, y_l,
                                                out, ny, Hcut, HcutM);
    } else {
        gpr_full<<<blocks, TPB, 0, stream>>>(x, x_l, y_l, out, nx, ny, Hcut);
    }
}

// Round 10
// 93.370 us; speedup vs baseline: 1.1528x; 1.1131x over previous
//
#include <hip/hip_runtime.h>
#include <math.h>

// GPR_58746562675312: haversine-windowed weighted mean.
//   m[y] = sum_x w(y,x)*x[x] / sum_x w(y,x),  w = d if d<0.25 else 0,
//   d = 12.756 * asin(sqrt(hav(y,x)));  out = [m (ny), 0.001 (ny)]
//
// R17: R13 (per-cell bucket) and R16 (compacted bucket + shfl search)
// BOTH land at ~45us main -- the bucket layout is the bottleneck, not
// the traversal. The sorted layout's main kernel measured ~11us (R8
// fit). Return to sorted layout; cut its build 4 dispatches -> 2:
//   N1 memsetAsync(histX|histY|curX|curY, 25.6KB)
//   N2 hist_kernel (R8-identical, global atomics)
//   N3 scan_scatter: 103 blocks; EACH block redundantly scans its
//      domain's 1600-cell hist in LDS (R8-proven 256-thr/CHUNK=7 scan,
//      6.4KB L2 load -- cheap in parallel, unlike R12's partial-matrix
//      reads), then scatters its 256-pt chunk via LDS cellStart +
//      global atomic cursor. Block 0 writes csX.
//   N4 gpr_binned: byte-identical to R8's proven main kernel.
// Model: 40 (harness ws-poison fill) + 4x5.5 nodes + (1+2+5+11) ~ 81us.
// Cutoff radius 1.123 deg (reference uses sin(D), not sin(D/2)).
// Boundary decisions: band +-5e-8 on hav -> CR fp32-chain emulation.

#define TPB    256
#define YPB    4      // y rows per block == waves per block (main kernel)
#define CH     256    // points per scatter chunk
#define NSTRIP 40
#define NLON   40
#define NCELLS (NSTRIP * NLON)
#define C_CELL   0.25f
#define INV_CELL 4.0f
#define RLAT     1.1250f   // conservative window radius in degrees

__device__ __forceinline__ float sin_poly(float a) {
    float t = a * a;   // |a| <= 0.1746: err ~1e-9
    return a * fmaf(t, fmaf(t, 8.3333333e-3f, -0.16666667f), 1.0f);
}
__device__ __forceinline__ float cos_poly(float a) {
    float t = a * a;   // err ~2e-11
    return fmaf(t, fmaf(t, fmaf(t, -1.3888889e-3f, 4.1666668e-2f), -0.5f), 1.0f);
}
__device__ __forceinline__ int cell_of(float lon, float lat) {
    int s = (int)(lat * INV_CELL); s = min(max(s, 0), NSTRIP - 1);
    int l = (int)(lon * INV_CELL); l = min(max(l, 0), NLON - 1);
    return s * NLON + l;
}

// ---- build 1: histogram (R8-identical; hist pre-zeroed by memset) -----

__global__ __launch_bounds__(TPB) void hist_kernel(
    const float* __restrict__ x_l, const float* __restrict__ y_l,
    int* __restrict__ histX, int* __restrict__ histY, int nx, int ny)
{
    int i = blockIdx.x * TPB + threadIdx.x;
    if (i < nx) {
        atomicAdd(&histX[cell_of(x_l[2 * i], x_l[2 * i + 1])], 1);
    } else if (i < nx + ny) {
        int j = i - nx;
        atomicAdd(&histY[cell_of(y_l[2 * j], y_l[2 * j + 1])], 1);
    }
}

// ---- build 2: redundant per-block LDS scan + chunk scatter ------------
// blocks [0,nbx): x chunks; [nbx,nbx+nby): y chunks. Each block scans
// its domain's full hist into LDS (R8-proven shape), then scatters its
// 256-pt chunk: pos = cs_lds[cell] + atomicAdd(&curGlobal[cell], 1).

__global__ __launch_bounds__(TPB) void scan_scatter(
    const float* __restrict__ x, const float* __restrict__ x_l,
    const float* __restrict__ y_l,
    const int* __restrict__ histX, const int* __restrict__ histY,
    int* __restrict__ curX, int* __restrict__ curY,
    float4* __restrict__ sortedA, float2* __restrict__ sortedRaw,
    float*  __restrict__ sortedX,
    float2* __restrict__ sortedYL, int* __restrict__ sortedYIdx,
    int* __restrict__ csX, int nx, int ny, int nbx)
{
    const int CHUNK = (NCELLS + TPB - 1) / TPB;   // 7
    __shared__ int sums[TPB];
    __shared__ int cs[NCELLS];
    const int tid = threadIdx.x;
    const float d2r = 0.017453292519943295f;

    const bool isX = ((int)blockIdx.x < nbx);
    const int* hist = isX ? histX : histY;
    int*       cur  = isX ? curX  : curY;

    // exclusive scan of hist -> cs (LDS); body = R8's proven scan_kernel
    int base = tid * CHUNK;
    int local[7];
    int s = 0;
    #pragma unroll
    for (int j = 0; j < CHUNK; ++j) {
        int idx = base + j;
        int v = (idx < NCELLS) ? hist[idx] : 0;
        local[j] = s; s += v;
    }
    sums[tid] = s;
    __syncthreads();
    for (int off = 1; off < TPB; off <<= 1) {
        int t = (tid >= off) ? sums[tid - off] : 0;
        __syncthreads();
        sums[tid] += t;
        __syncthreads();
    }
    int excl = (tid > 0) ? sums[tid - 1] : 0;
    #pragma unroll
    for (int j = 0; j < CHUNK; ++j) {
        int idx = base + j;
        if (idx < NCELLS) {
            int v = excl + local[j];
            cs[idx] = v;
            if (isX && blockIdx.x == 0) csX[idx] = v;
        }
    }
    if (isX && blockIdx.x == 0 && tid == TPB - 1) csX[NCELLS] = sums[TPB - 1];
    __syncthreads();

    // scatter this block's chunk (1 point/thread)
    const int bd = isX ? blockIdx.x : blockIdx.x - nbx;
    const int n  = isX ? nx : ny;
    int i = bd * CH + tid;
    if (i < n) {
        const float* loc = isX ? x_l : y_l;
        float lon = loc[2 * i], lat = loc[2 * i + 1];
        int cell = cell_of(lon, lat);
        int pos = cs[cell] + atomicAdd(&cur[cell], 1);
        if (isX) {
            float al = lat * d2r, ao = lon * d2r;
            sortedA[pos]   = make_float4(sin_poly(al), cos_poly(al),
                                         sin_poly(ao), cos_poly(ao));
            sortedRaw[pos] = make_float2(lon, lat);
            sortedX[pos]   = x[i];
        } else {
            sortedYL[pos]   = make_float2(lon, lat);
            sortedYIdx[pos] = i;
        }
    }
}

// ---- main kernel (binned, y processed in sorted order; R8-identical) ---

__global__ __launch_bounds__(TPB) void gpr_binned(
    const float4* __restrict__ sortedA,   // (slat, clat, slon, clon)
    const float2* __restrict__ sortedRaw, // (lon, lat) raw degrees
    const float*  __restrict__ sortedX,
    const int*    __restrict__ cellStart, // [NCELLS+1] (x grid)
    const float2* __restrict__ sortedYL,
    const int*    __restrict__ sortedYIdx,
    float* __restrict__ out, int ny, float Hcut, float HcutM)
{
    const int tid  = threadIdx.x;
    const int wave = tid >> 6;
    const int lane = tid & 63;
    const int j    = blockIdx.x * YPB + wave;   // sorted-y position

    const float d2r    = 0.017453292519943295f;
    const float r2d    = 57.29577951308232f;
    const float THRESH = 0.25f;
    const float DIAM   = 12.756f;
    const float DIAM6  = 12.756f / 6.0f;
    const float EPS_H  = 5e-8f;

    int   yidx  = 0;
    float lon_y = 0.0f, lat_y = 0.0f;
    if (j < ny) {
        yidx = sortedYIdx[j];
        float2 p = sortedYL[j];
        lon_y = p.x; lat_y = p.y;
    }
    const float sly   = sin_poly(lat_y * d2r);
    const float cly   = cos_poly(lat_y * d2r);
    const float slony = sin_poly(lon_y * d2r);
    const float clony = cos_poly(lon_y * d2r);

    float accw = 0.0f, accwx = 0.0f;

    const int s0 = max(0,          (int)floorf((lat_y - RLAT) * INV_CELL));
    const int s1 = min(NSTRIP - 1, (int)floorf((lat_y + RLAT) * INV_CELL));

    for (int s = s0; s <= s1; ++s) {
        // conservative min |dlat| from y to this strip
        float slo = s * C_CELL, shi = slo + C_CELL;
        float dmin = fmaxf(0.0f, fmaxf(slo - lat_y, lat_y - shi));
        float de   = fmaxf(0.0f, dmin - 3e-3f);
        float sd_  = sin_poly(de * d2r);
        float rem  = HcutM - sd_ * sd_;
        if (rem <= 0.0f) continue;
        // conservative min cos(lat_x)*cos(lat_y) over the strip
        float ccm = cos_poly(fminf(shi, 10.0f) * d2r) * cly * 0.999999f;
        float W   = asinf(fminf(1.0f, sqrtf(rem / ccm))) * r2d + 4e-3f;
        int lo = min(NLON - 1, max(0, (int)floorf((lon_y - W) * INV_CELL)));
        int hi = min(NLON - 1, max(0, (int)floorf((lon_y + W) * INV_CELL)));
        int p0 = cellStart[s * NLON + lo];
        int p1 = cellStart[s * NLON + hi + 1];

        for (int k = p0 + lane; k < p1; k += 64) {
            float4 e  = sortedA[k];
            float  xv = sortedX[k];

            float sl  = fmaf(e.x, cly,   -(e.y * sly));    // sin(dlat*d2r)
            float sd  = fmaf(e.z, clony, -(e.w * slony));  // sin(dlon*d2r)
            float cxy = e.y * cly;
            float hav = fmaf(sl, sl, cxy * (sd * sd));

            float tb  = hav - Hcut;
            float r   = __builtin_amdgcn_sqrtf(hav);
            float d   = r * fmaf(hav, DIAM6, DIAM);

            float w;
            if (__builtin_expect(fabsf(tb) < EPS_H, 0)) {
                // Emulate the numpy fp32 chain, every step correctly rounded.
                float2 raw = sortedRaw[k];
                float lonx = raw.x, latx = raw.y;

                float dlat = __fsub_rn(latx, lat_y);
                float alat = __fmul_rn(dlat, d2r);
                float slf  = (float)sin((double)alat);        // CR fp32 sin
                float h1   = __fmul_rn(slf, slf);

                float axl  = __fmul_rn(latx,  d2r);
                float ayl  = __fmul_rn(lat_y, d2r);
                float cxf  = (float)cos((double)axl);         // CR fp32 cos
                float cyf  = (float)cos((double)ayl);
                float cc   = __fmul_rn(cxf, cyf);

                float dlon = __fsub_rn(lonx, lon_y);
                float alon = __fmul_rn(dlon, d2r);
                float sdf  = (float)sin((double)alon);
                float h2   = __fmul_rn(sdf, sdf);

                float hv   = __fadd_rn(h1, __fmul_rn(cc, h2));
                float r32  = (float)sqrt((double)hv);         // CR fp32 sqrt
                float as32 = (float)asin((double)r32);        // CR fp32 asin
                float dnp  = __fmul_rn(DIAM, as32);
                w = (dnp < THRESH) ? dnp : 0.0f;
            } else {
                w = (tb < 0.0f) ? d : 0.0f;
            }

            accw += w;
            accwx = fmaf(w, xv, accwx);
        }
    }

    #pragma unroll
    for (int off = 32; off > 0; off >>= 1) {
        accw  += __shfl_xor(accw,  off, 64);
        accwx += __shfl_xor(accwx, off, 64);
    }

    if (lane == 0 && j < ny) {
        float m = (accw > 0.0f) ? (accwx / fmaxf(accw, 1e-12f)) : 0.0f;
        out[yidx]      = m;
        out[ny + yidx] = 0.001f;
    }
}

// ---- fallback: full scan (used only if ws is too small) ---------------

__global__ __launch_bounds__(TPB) void gpr_full(
    const float* __restrict__ x, const float* __restrict__ x_l,
    const float* __restrict__ y_l, float* __restrict__ out,
    int nx, int ny, float Hcut)
{
    __shared__ float4 tA[1024];
    __shared__ float  tX[1024];

    const int tid  = threadIdx.x;
    const int wave = tid >> 6;
    const int lane = tid & 63;
    const int y    = blockIdx.x * YPB + wave;

    const float d2r    = 0.017453292519943295f;
    const float THRESH = 0.25f;
    const float DIAM   = 12.756f;
    const float DIAM6  = 12.756f / 6.0f;
    const float EPS_H  = 5e-8f;

    float lon_y = 0.0f, lat_y = 0.0f;
    if (y < ny) { lon_y = y_l[2 * y]; lat_y = y_l[2 * y + 1]; }
    const float sly   = sin_poly(lat_y * d2r);
    const float cly   = cos_poly(lat_y * d2r);
    const float slony = sin_poly(lon_y * d2r);
    const float clony = cos_poly(lon_y * d2r);

    float accw = 0.0f, accwx = 0.0f;

    const int ntiles = (nx + 1023) / 1024;
    for (int t = 0; t < ntiles; ++t) {
        const int base = t * 1024;
        __syncthreads();
        #pragma unroll
        for (int jj = 0; jj < 1024 / TPB; ++jj) {
            int idx = jj * TPB + tid, i = base + idx;
            if (i < nx) {
                float lon = x_l[2 * i], lat = x_l[2 * i + 1];
                tA[idx] = make_float4(sin_poly(lat * d2r), cos_poly(lat * d2r),
                                      sin_poly(lon * d2r), cos_poly(lon * d2r));
                tX[idx] = x[i];
            }
        }
        __syncthreads();

        const int tn = min(1024, nx - base);
        for (int k = lane; k < tn; k += 64) {
            float4 e  = tA[k];
            float  xv = tX[k];
            float sl  = fmaf(e.x, cly,   -(e.y * sly));
            float sd  = fmaf(e.z, clony, -(e.w * slony));
            float cxy = e.y * cly;
            float hav = fmaf(sl, sl, cxy * (sd * sd));
            float tb  = hav - Hcut;
            float r   = __builtin_amdgcn_sqrtf(hav);
            float d   = r * fmaf(hav, DIAM6, DIAM);
            float w;
            if (__builtin_expect(fabsf(tb) < EPS_H, 0)) {
                int   i    = base + k;
                float lonx = x_l[2 * i], latx = x_l[2 * i + 1];
                float dlat = __fsub_rn(latx, lat_y);
                float alat = __fmul_rn(dlat, d2r);
                float slf  = (float)sin((double)alat);
                float h1   = __fmul_rn(slf, slf);
                float axl  = __fmul_rn(latx,  d2r);
                float ayl  = __fmul_rn(lat_y, d2r);
                float cxf  = (float)cos((double)axl);
                float cyf  = (float)cos((double)ayl);
                float cc   = __fmul_rn(cxf, cyf);
                float dlon = __fsub_rn(lonx, lon_y);
                float alon = __fmul_rn(dlon, d2r);
                float sdf  = (float)sin((double)alon);
                float h2   = __fmul_rn(sdf, sdf);
                float hv   = __fadd_rn(h1, __fmul_rn(cc, h2));
                float r32  = (float)sqrt((double)hv);
                float as32 = (float)asin((double)r32);
                float dnp  = __fmul_rn(DIAM, as32);
                w = (dnp < THRESH) ? dnp : 0.0f;
            } else {
                w = (tb < 0.0f) ? d : 0.0f;
            }
            accw += w;
            accwx = fmaf(w, xv, accwx);
        }
    }

    #pragma unroll
    for (int off = 32; off > 0; off >>= 1) {
        accw  += __shfl_xor(accw,  off, 64);
        accwx += __shfl_xor(accwx, off, 64);
    }

    if (lane == 0 && y < ny) {
        float m = (accw > 0.0f) ? (accwx / fmaxf(accw, 1e-12f)) : 0.0f;
        out[y]      = m;
        out[ny + y] = 0.001f;
    }
}

// ---- launcher ----------------------------------------------------------

extern "C" void kernel_launch(void* const* d_in, const int* in_sizes, int n_in,
                              void* d_out, int out_size, void* d_ws, size_t ws_size,
                              hipStream_t stream) {
    const float* x   = (const float*)d_in[0];
    const float* x_l = (const float*)d_in[1];
    const float* y_l = (const float*)d_in[2];
    float* out = (float*)d_out;

    const int nx = in_sizes[0];        // 20000
    const int ny = in_sizes[2] / 2;    // 6000

    const int nbx = (nx + CH - 1) / CH;   // 79
    const int nby = (ny + CH - 1) / CH;   // 24

    // hav threshold, fp64 on host: sin^2(0.25/12.756)
    double th = 0.25 / 12.756;
    double s  = sin(th);
    float Hcut  = (float)(s * s);
    float HcutM = (float)(s * s * 1.001);   // margin for window pruning

    // ws layout (16B-aligned start; 8/4-byte members naturally aligned)
    size_t offA   = 0;
    size_t offRaw = offA   + (size_t)nx * sizeof(float4);       // 16 nx
    size_t offYL  = offRaw + (size_t)nx * sizeof(float2);       //  8 nx
    size_t offX   = offYL  + (size_t)ny * sizeof(float2);       //  8 ny
    size_t offYI  = offX   + (size_t)nx * sizeof(float);        //  4 nx
    size_t offCSX = offYI  + (size_t)ny * sizeof(int);          //  4 ny
    size_t offZ   = offCSX + (size_t)(NCELLS + 1) * sizeof(int);
    // contiguous zero region: histX | histY | curX | curY
    size_t offHX  = offZ;
    size_t offHY  = offHX  + (size_t)NCELLS * sizeof(int);
    size_t offCuX = offHY  + (size_t)NCELLS * sizeof(int);
    size_t offCuY = offCuX + (size_t)NCELLS * sizeof(int);
    size_t total  = offCuY + (size_t)NCELLS * sizeof(int);
    size_t zbytes = total - offZ;                               // 25.6 KB

    const int blocks = (ny + YPB - 1) / YPB;

    if (ws_size >= total) {
        float4* sortedA    = (float4*)((char*)d_ws + offA);
        float2* sortedRaw  = (float2*)((char*)d_ws + offRaw);
        float2* sortedYL   = (float2*)((char*)d_ws + offYL);
        float*  sortedX    = (float*) ((char*)d_ws + offX);
        int*    sortedYIdx = (int*)   ((char*)d_ws + offYI);
        int*    csX        = (int*)   ((char*)d_ws + offCSX);
        int*    histX      = (int*)   ((char*)d_ws + offHX);
        int*    histY      = (int*)   ((char*)d_ws + offHY);
        int*    curX       = (int*)   ((char*)d_ws + offCuX);
        int*    curY       = (int*)   ((char*)d_ws + offCuY);

        hipMemsetAsync((char*)d_ws + offZ, 0, zbytes, stream);
        int nb = (nx + ny + TPB - 1) / TPB;
        hist_kernel<<<nb, TPB, 0, stream>>>(x_l, y_l, histX, histY, nx, ny);
        scan_scatter<<<nbx + nby, TPB, 0, stream>>>(x, x_l, y_l,
                                                    histX, histY, curX, curY,
                                                    sortedA, sortedRaw, sortedX,
                                                    sortedYL, sortedYIdx,
                                                    csX, nx, ny, nbx);
        gpr_binned<<<blocks, TPB, 0, stream>>>(sortedA, sortedRaw, sortedX,
                                               csX, sortedYL, sortedYIdx,
                                               out, ny, Hcut, HcutM);
    } else {
        gpr_full<<<blocks, TPB, 0, stream>>>(x, x_l, y_l, out, nx, ny, Hcut);
    }
}